// Round 1
// baseline (43155.954 us; speedup 1.0000x reference)
//
#include <hip/hip_runtime.h>
#include <hip/hip_bf16.h>
#include <math.h>

// ---------------------------------------------------------------------------
// HybridGemmaDiT forward, fp32 baseline.
// B=64, S=256 (16x16), D=768, L=8, NH=4, HD=192.
// Key simplification: scores = rot(q@Q^T) . rot(k@Q^T)  (trailing @Q cancels
// because Q Q^T = I to ~1e-6).  Q^T is folded into the qkv weights once per
// call, so per-layer q,k come out of the qkv GEMM pre-rotated.
// ---------------------------------------------------------------------------

#define DEV static __device__ __forceinline__

constexpr int Bb = 64, Ss = 256, Dd = 768, Ll = 8, NHh = 4, HDd = 192;
constexpr int M_TOK = Bb * Ss;                 // 16384
constexpr float EPS_RMS = 1.1920929e-07f;
constexpr float ATT_SCALE = 0.07216878364870322f;  // 1/sqrt(192)

// ---- workspace layout (floats) --------------------------------------------
constexpr size_t OFF_SPINS  = 0;                                   // 64*8
constexpr size_t OFF_SCALEF = OFF_SPINS + 64 * 8;                  // 64*12
constexpr size_t OFF_QT     = OFF_SCALEF + 64 * 12;                // 8*192*192
constexpr size_t OFF_COS    = OFF_QT + (size_t)Ll * HDd * HDd;     // 256*192
constexpr size_t OFF_SIN    = OFF_COS + (size_t)Ss * HDd;
constexpr size_t OFF_WEFF   = OFF_SIN + (size_t)Ss * HDd;          // 8*768*2304
constexpr size_t OFF_X      = OFF_WEFF + (size_t)Ll * Dd * 3 * Dd;
constexpr size_t OFF_H      = OFF_X + (size_t)M_TOK * Dd;
constexpr size_t OFF_PROJ   = OFF_H + (size_t)M_TOK * Dd;
constexpr size_t OFF_ARENA  = OFF_PROJ + (size_t)M_TOK * Dd;
// arena: [q | k | v | attn] during attention;  hidden (16384*3072) during MLP
constexpr size_t ARENA_K    = (size_t)Bb * NHh * Ss * HDd;         // 12,582,912
constexpr size_t ARENA_ATTN = 3 * ARENA_K;
constexpr size_t WS_FLOATS  = OFF_ARENA + (size_t)M_TOK * 4 * Dd;  // ~392 MiB

DEV float sigmoidf_(float x) { return 1.0f / (1.0f + expf(-x)); }
DEV float geluf_(float g)    { return 0.5f * g * (1.0f + erff(g * 0.7071067811865476f)); }

// ---------------------------------------------------------------------------
__global__ void spins_kernel(const float* __restrict__ logsnr, float* __restrict__ spins) {
    int b = threadIdx.x;
    if (b < 64) {
        float v = logsnr[b];
#pragma unroll
        for (int j = 0; j < 4; ++j) {
            float ang = v * (float)(1 << j);
            spins[b * 8 + j]     = sinf(ang);
            spins[b * 8 + 4 + j] = cosf(ang);
        }
    }
}

__global__ void rope_table_kernel(float* __restrict__ cosb, float* __restrict__ sinb) {
    int s = blockIdx.x;      // 256
    int j = threadIdx.x;     // 192
    int y = s >> 4, x = s & 15;
    int base = j % 96;
    float coord, invf;
    if (base < 48) { invf = expf(-(float)base * (2.0f / 96.0f) * 9.210340371976184f); coord = (float)y; }
    else { int i = base - 48; invf = expf(-(float)i * (2.0f / 96.0f) * 9.210340371976184f); coord = (float)x; }
    float f = coord * invf, sv, cv;
    sincosf(f, &sv, &cv);
    cosb[s * 192 + j] = cv;
    sinb[s * 192 + j] = sv;
}

// one block per layer; Q kept in LDS (192x193 padded = 148 KB)
__global__ __launch_bounds__(256) void householder_kernel(const float* __restrict__ hh_vs,
                                                          float* __restrict__ qt) {
    __shared__ float Q[192][193];
    __shared__ float v[192];
    __shared__ float w[192];
    __shared__ float red[256];
    int l = blockIdx.x, t = threadIdx.x;
    for (int i = t; i < 192 * 192; i += 256) { int r = i / 192, c = i % 192; Q[r][c] = (r == c) ? 1.0f : 0.0f; }
    __syncthreads();
    for (int step = 0; step < 96; ++step) {
        if (t < 192) v[t] = hh_vs[((size_t)l * 96 + step) * 192 + t];
        red[t] = (t < 192) ? 0.0f : 0.0f;
        if (t < 192) red[t] = v[t] * v[t];   // own value, no barrier needed
        if (t >= 192) red[t] = 0.0f;
        __syncthreads();
        for (int s = 128; s > 0; s >>= 1) { if (t < s) red[t] += red[t + s]; __syncthreads(); }
        float c2 = 2.0f / (red[0] + 1e-8f);
        if (t < 192) { float acc = 0.f; for (int i = 0; i < 192; ++i) acc += v[i] * Q[i][t]; w[t] = acc; }
        __syncthreads();
        for (int i = t; i < 192 * 192; i += 256) { int r = i / 192, c = i % 192; Q[r][c] -= c2 * v[r] * w[c]; }
        __syncthreads();
    }
    // qt[d][j] = Q[j][d]  (so generic GEMM with B=qt computes  W @ Q^T)
    for (int i = t; i < 192 * 192; i += 256) {
        int j = i % 192, d = i / 192;
        qt[((size_t)l * 192 + d) * 192 + j] = Q[j][d];
    }
}

// W_eff q/k head-blocks <- qkv_w block @ Q^T.  grid (3, 12, 64), 256 thr.
__global__ __launch_bounds__(256) void fold_kernel(const float* __restrict__ qkv_w,
                                                   const float* __restrict__ qt,
                                                   float* __restrict__ weff) {
    int z = blockIdx.z;
    int l = z >> 3, which = (z >> 2) & 1, head = z & 3;
    const float* A  = qkv_w + (size_t)l * 768 * 2304 + (size_t)which * 768 + head * 192;
    const float* Bq = qt + (size_t)l * 192 * 192;
    float* C        = weff + (size_t)l * 768 * 2304 + (size_t)which * 768 + head * 192;
    int row0 = blockIdx.y * 64, col0 = blockIdx.x * 64;
    __shared__ float As[64][65];
    __shared__ float Bs[64][65];
    int tid = threadIdx.x, tx = tid & 15, ty = tid >> 4;
    float acc[4][4] = {};
    for (int k0 = 0; k0 < 192; k0 += 64) {
        for (int i = tid; i < 1024; i += 256) {
            int r = i >> 4, kq = i & 15;
            float4 va = *(const float4*)(A + (size_t)(row0 + r) * 2304 + k0 + kq * 4);
            As[kq * 4 + 0][r] = va.x; As[kq * 4 + 1][r] = va.y; As[kq * 4 + 2][r] = va.z; As[kq * 4 + 3][r] = va.w;
        }
        for (int i = tid; i < 1024; i += 256) {
            int r = i >> 4, nq = i & 15;
            float4 vb = *(const float4*)(Bq + (size_t)(k0 + r) * 192 + col0 + nq * 4);
            Bs[r][nq * 4 + 0] = vb.x; Bs[r][nq * 4 + 1] = vb.y; Bs[r][nq * 4 + 2] = vb.z; Bs[r][nq * 4 + 3] = vb.w;
        }
        __syncthreads();
        for (int k = 0; k < 64; ++k) {
            float a[4], bb[4];
#pragma unroll
            for (int m = 0; m < 4; ++m) a[m] = As[k][ty * 4 + m];
#pragma unroll
            for (int n = 0; n < 4; ++n) bb[n] = Bs[k][tx * 4 + n];
#pragma unroll
            for (int m = 0; m < 4; ++m)
#pragma unroll
                for (int n = 0; n < 4; ++n) acc[m][n] = fmaf(a[m], bb[n], acc[m][n]);
        }
        __syncthreads();
    }
#pragma unroll
    for (int m = 0; m < 4; ++m)
#pragma unroll
        for (int n = 0; n < 4; ++n)
            C[(size_t)(row0 + ty * 4 + m) * 2304 + col0 + tx * 4 + n] = acc[m][n];
}

__global__ __launch_bounds__(256) void patch_embed_kernel(const float* __restrict__ z_t,
                                                          const float* __restrict__ spins,
                                                          const float* __restrict__ patch_w,
                                                          const float* __restrict__ patch_b,
                                                          float* __restrict__ x) {
    int bs = blockIdx.x;
    int b = bs >> 8, s = bs & 255;
    int gy = s >> 4, gx = s & 15;
    __shared__ float in20[20];
    int t = threadIdx.x;
    if (t < 12) {
        int c = t >> 2, py = (t >> 1) & 1, px = t & 1;
        in20[t] = z_t[(((size_t)b * 3 + c) * 32 + (2 * gy + py)) * 32 + (2 * gx + px)];
    } else if (t < 20) {
        in20[t] = spins[b * 8 + (t - 12)];
    }
    __syncthreads();
    for (int d = t; d < 768; d += 256) {
        float acc = patch_b[d];
#pragma unroll
        for (int i = 0; i < 20; ++i) acc += in20[i] * patch_w[i * 768 + d];
        x[(size_t)bs * 768 + d] = acc;
    }
}

__global__ __launch_bounds__(256) void rmsnorm_kernel(const float* __restrict__ x, float* __restrict__ h) {
    int row = blockIdx.x, t = threadIdx.x;
    const float* xr = x + (size_t)row * 768;
    float a0 = xr[t], a1 = xr[t + 256], a2 = xr[t + 512];
    __shared__ float red[256];
    red[t] = a0 * a0 + a1 * a1 + a2 * a2;
    __syncthreads();
    for (int s = 128; s > 0; s >>= 1) { if (t < s) red[t] += red[t + s]; __syncthreads(); }
    float sc = 1.0f / sqrtf(red[0] / 768.0f + EPS_RMS);
    float* hr = h + (size_t)row * 768;
    hr[t] = a0 * sc; hr[t + 256] = a1 * sc; hr[t + 512] = a2 * sc;
}

// ---- generic fp32 GEMM, 128x128x16 tile, 8x8 microtile, 256 threads -------
// EPI: 0=store(+bias)  1=qkv-scatter  2=gate(sigmoid, X+=A*sig)  3=C=val*gelu(C)
//      4=C+=v
template <int EPI>
__global__ __launch_bounds__(256) void gemm128(const float* __restrict__ A, int lda,
                                               const float* __restrict__ B, int ldb,
                                               float* __restrict__ C, int ldc, int K,
                                               const float* __restrict__ bias,
                                               float* __restrict__ X) {
    constexpr int BM = 128, BN = 128, BK = 16, TM = 8, TN = 8;
    __shared__ float As[BK][BM + 4];
    __shared__ float Bs[BK][BN + 4];
    int tid = threadIdx.x;
    int tx = tid & 15, ty = tid >> 4;
    int row0 = blockIdx.y * BM, col0 = blockIdx.x * BN;
    float acc[TM][TN] = {};
    for (int k0 = 0; k0 < K; k0 += BK) {
#pragma unroll
        for (int i = 0; i < 2; ++i) {
            int idx = tid + i * 256;              // 0..511
            int r = idx >> 2, kq = idx & 3;
            float4 va = *(const float4*)(A + (size_t)(row0 + r) * lda + k0 + kq * 4);
            As[kq * 4 + 0][r] = va.x; As[kq * 4 + 1][r] = va.y;
            As[kq * 4 + 2][r] = va.z; As[kq * 4 + 3][r] = va.w;
        }
#pragma unroll
        for (int i = 0; i < 2; ++i) {
            int idx = tid + i * 256;
            int r = idx >> 5, nq = idx & 31;
            float4 vb = *(const float4*)(B + (size_t)(k0 + r) * ldb + col0 + nq * 4);
            *((float4*)&Bs[r][nq * 4]) = vb;
        }
        __syncthreads();
#pragma unroll
        for (int k = 0; k < BK; ++k) {
            float a[TM], bb[TN];
            *(float4*)&a[0]  = *(const float4*)&As[k][ty * TM];
            *(float4*)&a[4]  = *(const float4*)&As[k][ty * TM + 4];
            *(float4*)&bb[0] = *(const float4*)&Bs[k][tx * TN];
            *(float4*)&bb[4] = *(const float4*)&Bs[k][tx * TN + 4];
#pragma unroll
            for (int m = 0; m < TM; ++m)
#pragma unroll
                for (int n = 0; n < TN; ++n) acc[m][n] = fmaf(a[m], bb[n], acc[m][n]);
        }
        __syncthreads();
    }
#pragma unroll
    for (int m = 0; m < TM; ++m) {
        int i = row0 + ty * TM + m;
#pragma unroll
        for (int n = 0; n < TN; ++n) {
            int j = col0 + tx * TN + n;
            float v = acc[m][n];
            if (bias) v += bias[j];
            if constexpr (EPI == 0) {
                C[(size_t)i * ldc + j] = v;
            } else if constexpr (EPI == 1) {     // X = arena base; scatter q/k/v head-major
                int which = j / 768;
                int rem = j - which * 768;
                int head = rem / 192;
                int hd = rem - head * 192;
                int b = i >> 8, s = i & 255;
                X[(size_t)which * ARENA_K + (((size_t)(b * 4 + head)) * 256 + s) * 192 + hd] = v;
            } else if constexpr (EPI == 2) {     // A = proj ; X = x ; v includes gate_b
                float p = A[(size_t)i * lda + j];
                X[(size_t)i * ldc + j] += p * sigmoidf_(v);
            } else if constexpr (EPI == 3) {     // C holds g; v = val(+bias)
                float g = C[(size_t)i * ldc + j];
                C[(size_t)i * ldc + j] = v * geluf_(g);
            } else if constexpr (EPI == 4) {
                C[(size_t)i * ldc + j] += v;
            }
        }
    }
}

// in-place RoPE on [q|k] arena rows (131072 rows x 192), pair (j, j+96)
__global__ __launch_bounds__(256) void rope_kernel(float* __restrict__ qk,
                                                   const float* __restrict__ cosb,
                                                   const float* __restrict__ sinb) {
    size_t gid = (size_t)blockIdx.x * 256 + threadIdx.x;   // 131072*96 total
    int row = (int)(gid / 96);
    int j = (int)(gid % 96);
    int s = row & 255;
    float* p = qk + (size_t)row * 192;
    float t1 = p[j], t2 = p[j + 96];
    float c1 = cosb[s * 192 + j],      s1 = sinb[s * 192 + j];
    float c2 = cosb[s * 192 + j + 96], s2 = sinb[s * 192 + j + 96];
    p[j]      = t1 * c1 - t2 * s1;
    p[j + 96] = t2 * c2 + t1 * s2;
}

// attention: grid (8 qtiles, NH, B), 256 threads, two-pass softmax in LDS
__global__ __launch_bounds__(256) void attn_kernel(const float* __restrict__ qb_,
                                                   const float* __restrict__ kb_,
                                                   const float* __restrict__ vb_,
                                                   float* __restrict__ attn, int glob) {
    int b = blockIdx.z, h = blockIdx.y, q0 = blockIdx.x * 32;
    const float* qb = qb_ + ((size_t)(b * 4 + h) * 256) * 192;
    const float* kb = kb_ + ((size_t)(b * 4 + h) * 256) * 192;
    const float* vb = vb_ + ((size_t)(b * 4 + h) * 256) * 192;
    __shared__ float qs[32][194];
    __shared__ float ks[64][193];
    __shared__ float sc[32][257];
    __shared__ float red8[32][9];
    int t = threadIdx.x;
    for (int i = t; i < 1536; i += 256) {        // 32 rows * 48 f4
        int r = i / 48, f = i % 48;
        float4 v4 = *(const float4*)(qb + (size_t)(q0 + r) * 192 + f * 4);
        qs[r][f * 4] = v4.x; qs[r][f * 4 + 1] = v4.y; qs[r][f * 4 + 2] = v4.z; qs[r][f * 4 + 3] = v4.w;
    }
    int qr = t >> 3, l8 = t & 7;
    int sq = q0 + qr, yq = sq >> 4, xq = sq & 15;
    for (int kt = 0; kt < 4; ++kt) {
        __syncthreads();
        for (int i = t; i < 3072; i += 256) {    // 64 rows * 48 f4
            int r = i / 48, f = i % 48;
            float4 v4 = *(const float4*)(kb + (size_t)(kt * 64 + r) * 192 + f * 4);
            ks[r][f * 4] = v4.x; ks[r][f * 4 + 1] = v4.y; ks[r][f * 4 + 2] = v4.z; ks[r][f * 4 + 3] = v4.w;
        }
        __syncthreads();
        int kc0 = l8 * 8;
        float a8[8] = {};
        for (int d = 0; d < 192; ++d) {
            float qv = qs[qr][d];
#pragma unroll
            for (int i = 0; i < 8; ++i) a8[i] = fmaf(qv, ks[kc0 + i][d], a8[i]);
        }
#pragma unroll
        for (int i = 0; i < 8; ++i) {
            int sk = kt * 64 + kc0 + i, yk = sk >> 4, xk = sk & 15;
            int dy = yq - yk, dx = xq - xk;
            bool keep = glob || (dy * dy + dx * dx) < 7;   // d2 < 6.25
            sc[qr][kt * 64 + kc0 + i] = keep ? a8[i] * ATT_SCALE : -1e30f;
        }
    }
    __syncthreads();
    float m = -3e38f;
    for (int c = l8; c < 256; c += 8) m = fmaxf(m, sc[qr][c]);
    red8[qr][l8] = m;
    __syncthreads();
    if (l8 == 0) { float mm = red8[qr][0]; for (int i = 1; i < 8; ++i) mm = fmaxf(mm, red8[qr][i]); red8[qr][8] = mm; }
    __syncthreads();
    float rm = red8[qr][8];
    float e = 0.f;
    for (int c = l8; c < 256; c += 8) { float p = expf(sc[qr][c] - rm); sc[qr][c] = p; e += p; }
    __syncthreads();
    red8[qr][l8] = e;
    __syncthreads();
    if (l8 == 0) { float ss = 0.f; for (int i = 0; i < 8; ++i) ss += red8[qr][i]; red8[qr][8] = ss; }
    __syncthreads();
    float inv = 1.0f / red8[qr][8];
    for (int c = l8; c < 256; c += 8) sc[qr][c] *= inv;
    float out[24] = {};
    int d0 = l8 * 24;
    for (int vt = 0; vt < 4; ++vt) {
        __syncthreads();
        for (int i = t; i < 3072; i += 256) {
            int r = i / 48, f = i % 48;
            float4 v4 = *(const float4*)(vb + (size_t)(vt * 64 + r) * 192 + f * 4);
            ks[r][f * 4] = v4.x; ks[r][f * 4 + 1] = v4.y; ks[r][f * 4 + 2] = v4.z; ks[r][f * 4 + 3] = v4.w;
        }
        __syncthreads();
        for (int kc = 0; kc < 64; ++kc) {
            float p = sc[qr][vt * 64 + kc];
#pragma unroll
            for (int i = 0; i < 24; ++i) out[i] = fmaf(p, ks[kc][d0 + i], out[i]);
        }
    }
    float* dst = attn + ((size_t)(b * 256 + (q0 + qr))) * 768 + h * 192 + d0;
#pragma unroll
    for (int i = 0; i < 24; ++i) dst[i] = out[i];
}

__global__ __launch_bounds__(768) void scalef_kernel(const float* __restrict__ spins,
                                                     const float* __restrict__ sd1_w,
                                                     const float* __restrict__ sd1_b,
                                                     const float* __restrict__ sd2_w,
                                                     const float* __restrict__ sd2_b,
                                                     float* __restrict__ scalef) {
    int b = blockIdx.x, t = threadIdx.x;
    __shared__ float hid[768];
    __shared__ float sp[8];
    if (t < 8) sp[t] = spins[b * 8 + t];
    __syncthreads();
    float acc = sd1_b[t];
#pragma unroll
    for (int i = 0; i < 8; ++i) acc += sp[i] * sd1_w[i * 768 + t];
    hid[t] = acc * sigmoidf_(acc);
    __syncthreads();
    if (t < 12) {
        float o = sd2_b[t];
        for (int d = 0; d < 768; ++d) o += hid[d] * sd2_w[d * 12 + t];
        scalef[b * 12 + t] = expf(o);
    }
}

__global__ __launch_bounds__(192) void head_kernel(const float* __restrict__ xn,
                                                   const float* __restrict__ head_w,
                                                   const float* __restrict__ head_b,
                                                   const float* __restrict__ scalef,
                                                   float* __restrict__ out) {
    int bs = blockIdx.x;
    int b = bs >> 8, s = bs & 255;
    int t = threadIdx.x;
    int o = t >> 4, part = t & 15;
    const float* xr = xn + (size_t)bs * 768;
    float acc = 0.f;
    for (int d = part * 48; d < part * 48 + 48; ++d) acc += xr[d] * head_w[d * 12 + o];
    __shared__ float red[12][17];
    red[o][part] = acc;
    __syncthreads();
    if (t < 12) {
        float v = head_b[t];
        for (int i = 0; i < 16; ++i) v += red[t][i];
        v *= scalef[b * 12 + t];
        int c = t >> 2, py = (t >> 1) & 1, px = t & 1;
        int gy = s >> 4, gx = s & 15;
        out[(((size_t)b * 3 + c) * 32 + 2 * gy + py) * 32 + 2 * gx + px] = v;
    }
}

__global__ __launch_bounds__(256) void lpred_kernel(const float* __restrict__ xn,
                                                    const float* __restrict__ lam_w,
                                                    const float* __restrict__ lam_b,
                                                    float* __restrict__ out) {
    int b = blockIdx.x, t = threadIdx.x;
    float a0 = 0.f, a1 = 0.f, a2 = 0.f;
    const float* xb = xn + (size_t)b * 256 * 768;
    for (int s = 0; s < 256; ++s) {
        const float* xr = xb + (size_t)s * 768;
        a0 += xr[t]; a1 += xr[t + 256]; a2 += xr[t + 512];
    }
    float p = a0 * lam_w[t] + a1 * lam_w[t + 256] + a2 * lam_w[t + 512];
    __shared__ float red[256];
    red[t] = p;
    __syncthreads();
    for (int s2 = 128; s2 > 0; s2 >>= 1) { if (t < s2) red[t] += red[t + s2]; __syncthreads(); }
    if (t == 0) out[196608 + b] = red[0] / 256.0f + lam_b[0];
}

// ---------------------------------------------------------------------------
extern "C" void kernel_launch(void* const* d_in, const int* in_sizes, int n_in,
                              void* d_out, int out_size, void* d_ws, size_t ws_size,
                              hipStream_t stream) {
    const float* z_t     = (const float*)d_in[0];
    const float* logsnr  = (const float*)d_in[1];
    const float* qkv_w   = (const float*)d_in[2];
    const float* out_w   = (const float*)d_in[3];
    const float* gate_w  = (const float*)d_in[4];
    const float* gate_b  = (const float*)d_in[5];
    const float* mlpg_w  = (const float*)d_in[6];
    const float* mlpg_b  = (const float*)d_in[7];
    const float* mlpo_w  = (const float*)d_in[8];
    const float* mlpo_b  = (const float*)d_in[9];
    const float* hh_vs   = (const float*)d_in[10];
    const float* patch_w = (const float*)d_in[11];
    const float* patch_b = (const float*)d_in[12];
    const float* head_w  = (const float*)d_in[13];
    const float* head_b  = (const float*)d_in[14];
    const float* sd1_w   = (const float*)d_in[15];
    const float* sd1_b   = (const float*)d_in[16];
    const float* sd2_w   = (const float*)d_in[17];
    const float* sd2_b   = (const float*)d_in[18];
    const float* lam_w   = (const float*)d_in[19];
    const float* lam_b   = (const float*)d_in[20];

    float* ws     = (float*)d_ws;
    float* spins  = ws + OFF_SPINS;
    float* scalef = ws + OFF_SCALEF;
    float* qt     = ws + OFF_QT;
    float* cosb   = ws + OFF_COS;
    float* sinb   = ws + OFF_SIN;
    float* weff   = ws + OFF_WEFF;
    float* x      = ws + OFF_X;
    float* h      = ws + OFF_H;
    float* proj   = ws + OFF_PROJ;
    float* arena  = ws + OFF_ARENA;
    float* qbuf   = arena;
    float* kbuf   = arena + ARENA_K;
    float* vbuf   = arena + 2 * ARENA_K;
    float* attnb  = arena + ARENA_ATTN;
    float* hidden = arena;                    // aliases q/k/v/attn (dead by MLP)
    float* out    = (float*)d_out;

    spins_kernel<<<1, 64, 0, stream>>>(logsnr, spins);
    rope_table_kernel<<<256, 192, 0, stream>>>(cosb, sinb);
    householder_kernel<<<8, 256, 0, stream>>>(hh_vs, qt);
    hipMemcpyAsync(weff, qkv_w, (size_t)Ll * Dd * 3 * Dd * sizeof(float),
                   hipMemcpyDeviceToDevice, stream);
    fold_kernel<<<dim3(3, 12, 64), 256, 0, stream>>>(qkv_w, qt, weff);
    patch_embed_kernel<<<M_TOK, 256, 0, stream>>>(z_t, spins, patch_w, patch_b, x);

    for (int l = 0; l < Ll; ++l) {
        int glob = ((l + 1) % 4 == 0) ? 1 : 0;
        rmsnorm_kernel<<<M_TOK, 256, 0, stream>>>(x, h);
        gemm128<1><<<dim3(18, 128), 256, 0, stream>>>(h, 768,
            weff + (size_t)l * 768 * 2304, 2304, nullptr, 0, 768, nullptr, arena);
        rope_kernel<<<49152, 256, 0, stream>>>(arena, cosb, sinb);
        attn_kernel<<<dim3(8, 4, 64), 256, 0, stream>>>(qbuf, kbuf, vbuf, attnb, glob);
        gemm128<0><<<dim3(6, 128), 256, 0, stream>>>(attnb, 768,
            out_w + (size_t)l * 768 * 768, 768, proj, 768, 768, nullptr, nullptr);
        gemm128<2><<<dim3(6, 128), 256, 0, stream>>>(proj, 768,
            gate_w + (size_t)l * 768 * 768, 768, nullptr, 768, 768,
            gate_b + (size_t)l * 768, x);
        rmsnorm_kernel<<<M_TOK, 256, 0, stream>>>(x, h);
        gemm128<0><<<dim3(24, 128), 256, 0, stream>>>(h, 768,
            mlpg_w + (size_t)l * 768 * 6144, 6144, hidden, 3072, 768,
            mlpg_b + (size_t)l * 6144, nullptr);
        gemm128<3><<<dim3(24, 128), 256, 0, stream>>>(h, 768,
            mlpg_w + (size_t)l * 768 * 6144 + 3072, 6144, hidden, 3072, 768,
            mlpg_b + (size_t)l * 6144 + 3072, nullptr);
        gemm128<4><<<dim3(6, 128), 256, 0, stream>>>(hidden, 3072,
            mlpo_w + (size_t)l * 3072 * 768, 768, x, 768, 3072,
            mlpo_b + (size_t)l * 768, nullptr);
    }

    rmsnorm_kernel<<<M_TOK, 256, 0, stream>>>(x, h);
    scalef_kernel<<<64, 768, 0, stream>>>(spins, sd1_w, sd1_b, sd2_w, sd2_b, scalef);
    head_kernel<<<M_TOK, 192, 0, stream>>>(h, head_w, head_b, scalef, out);
    lpred_kernel<<<64, 256, 0, stream>>>(h, lam_w, lam_b, out);
}

// Round 2
// 14100.471 us; speedup vs baseline: 3.0606x; 3.0606x over previous
//
#include <hip/hip_runtime.h>
#include <hip/hip_bf16.h>
#include <math.h>

// ---------------------------------------------------------------------------
// HybridGemmaDiT forward.  B=64, S=256 (16x16), D=768, L=8, NH=4, HD=192.
// Round 2: all big GEMMs in bf16 MFMA (16x16x32), m97 structure:
//   128x128 tile, BK=32, 4 waves, global_load_lds(16B), 2-barrier K-loop,
//   XOR chunk-swizzle (pre-swizzled global source + swizzled LDS read).
// Weights are transposed+converted to bf16 [N][K] once per call.
// Residual x stays fp32; epilogues fp32; attention fp32 on bf16 q/k/v.
// scores = rot(q@Q^T).rot(k@Q^T) (trailing @Q cancels; folded into qkv_w).
// ---------------------------------------------------------------------------

#define DEV static __device__ __forceinline__

typedef float    f32x4 __attribute__((ext_vector_type(4)));
typedef short    s16x8 __attribute__((ext_vector_type(8)));
typedef unsigned short u16x8 __attribute__((ext_vector_type(8)));
typedef unsigned short u16x4 __attribute__((ext_vector_type(4)));

constexpr int Bb = 64, Ss = 256, Dd = 768, Ll = 8, NHh = 4, HDd = 192;
constexpr int M_TOK = Bb * Ss;                 // 16384
constexpr float EPS_RMS = 1.1920929e-07f;
constexpr float ATT_SCALE = 0.07216878364870322f;  // 1/sqrt(192)
constexpr size_t ARENA_K = (size_t)Bb * NHh * Ss * HDd;   // 12,582,912 elems

// ---- workspace layout (BYTES) ---------------------------------------------
constexpr size_t B_SPINS  = 0;                           // 512 f32
constexpr size_t B_SCALEF = 2048;                        // 768 f32
constexpr size_t B_QT     = 5120;                        // 8*192*192 f32
constexpr size_t B_COS    = B_QT + 1179648;              // 256*192 f32
constexpr size_t B_SIN    = B_COS + 196608;
constexpr size_t B_X      = B_SIN + 196608;              // 16384*768 f32
constexpr size_t B_H      = B_X + 50331648;              // 16384*768 bf16
constexpr size_t B_PROJ   = B_H + 25165824;              // 16384*768 bf16
constexpr size_t B_WEFFT  = B_PROJ + 25165824;           // 8*2304*768 bf16
constexpr size_t B_OUTWT  = B_WEFFT + 28311552;          // 8*768*768 bf16
constexpr size_t B_GATEWT = B_OUTWT + 9437184;
constexpr size_t B_MLPGT  = B_GATEWT + 9437184;          // 8*6144*768 bf16
constexpr size_t B_MLPOT  = B_MLPGT + 75497472;          // 8*768*3072 bf16
constexpr size_t B_ARENA  = B_MLPOT + 37748736;          // 4*12.58M bf16 (q,k,v,attn | hidden | weff_f32 tmp)

DEV float sigmoidf_(float x) { return 1.0f / (1.0f + expf(-x)); }
DEV float geluf_(float g)    { return 0.5f * g * (1.0f + erff(g * 0.7071067811865476f)); }
DEV unsigned short f2bf(float f) {
    union { float f; unsigned u; } a; a.f = f;
    unsigned u = a.u + 0x7fffu + ((a.u >> 16) & 1u);
    return (unsigned short)(u >> 16);
}
DEV float b2f(unsigned short u) {
    union { unsigned u; float f; } a; a.u = ((unsigned)u) << 16; return a.f;
}
DEV void gload16(const void* g, void* l) {
    __builtin_amdgcn_global_load_lds((const __attribute__((address_space(1))) void*)g,
                                     (__attribute__((address_space(3))) void*)l, 16, 0, 0);
}

// ---------------------------------------------------------------------------
__global__ void spins_kernel(const float* __restrict__ logsnr, float* __restrict__ spins) {
    int b = threadIdx.x;
    if (b < 64) {
        float v = logsnr[b];
#pragma unroll
        for (int j = 0; j < 4; ++j) {
            float ang = v * (float)(1 << j);
            spins[b * 8 + j]     = sinf(ang);
            spins[b * 8 + 4 + j] = cosf(ang);
        }
    }
}

__global__ void rope_table_kernel(float* __restrict__ cosb, float* __restrict__ sinb) {
    int s = blockIdx.x, j = threadIdx.x;
    int y = s >> 4, x = s & 15;
    int base = j % 96;
    float coord, invf;
    if (base < 48) { invf = expf(-(float)base * (2.0f / 96.0f) * 9.210340371976184f); coord = (float)y; }
    else { int i = base - 48; invf = expf(-(float)i * (2.0f / 96.0f) * 9.210340371976184f); coord = (float)x; }
    float f = coord * invf, sv, cv;
    sincosf(f, &sv, &cv);
    cosb[s * 192 + j] = cv;
    sinb[s * 192 + j] = sv;
}

// one block per layer; Q kept in LDS
__global__ __launch_bounds__(256) void householder_kernel(const float* __restrict__ hh_vs,
                                                          float* __restrict__ qt) {
    __shared__ float Q[192][193];
    __shared__ float v[192];
    __shared__ float w[192];
    __shared__ float red[256];
    int l = blockIdx.x, t = threadIdx.x;
    for (int i = t; i < 192 * 192; i += 256) { int r = i / 192, c = i % 192; Q[r][c] = (r == c) ? 1.0f : 0.0f; }
    __syncthreads();
    for (int step = 0; step < 96; ++step) {
        if (t < 192) v[t] = hh_vs[((size_t)l * 96 + step) * 192 + t];
        red[t] = 0.0f;
        if (t < 192) red[t] = v[t] * v[t];
        __syncthreads();
        for (int s = 128; s > 0; s >>= 1) { if (t < s) red[t] += red[t + s]; __syncthreads(); }
        float c2 = 2.0f / (red[0] + 1e-8f);
        if (t < 192) { float acc = 0.f; for (int i = 0; i < 192; ++i) acc += v[i] * Q[i][t]; w[t] = acc; }
        __syncthreads();
        for (int i = t; i < 192 * 192; i += 256) { int r = i / 192, c = i % 192; Q[r][c] -= c2 * v[r] * w[c]; }
        __syncthreads();
    }
    // qt[d][j] = Q[j][d]
    for (int i = t; i < 192 * 192; i += 256) {
        int j = i % 192, d = i / 192;
        qt[((size_t)l * 192 + d) * 192 + j] = Q[j][d];
    }
}

// W_eff q/k head-blocks <- qkv_w block @ Q^T (fp32).  grid (3, 12, 64).
__global__ __launch_bounds__(256) void fold_kernel(const float* __restrict__ qkv_w,
                                                   const float* __restrict__ qt,
                                                   float* __restrict__ weff) {
    int z = blockIdx.z;
    int l = z >> 3, which = (z >> 2) & 1, head = z & 3;
    const float* A  = qkv_w + (size_t)l * 768 * 2304 + (size_t)which * 768 + head * 192;
    const float* Bq = qt + (size_t)l * 192 * 192;
    float* C        = weff + (size_t)l * 768 * 2304 + (size_t)which * 768 + head * 192;
    int row0 = blockIdx.y * 64, col0 = blockIdx.x * 64;
    __shared__ float As[64][65];
    __shared__ float Bs[64][65];
    int tid = threadIdx.x, tx = tid & 15, ty = tid >> 4;
    float acc[4][4] = {};
    for (int k0 = 0; k0 < 192; k0 += 64) {
        for (int i = tid; i < 1024; i += 256) {
            int r = i >> 4, kq = i & 15;
            float4 va = *(const float4*)(A + (size_t)(row0 + r) * 2304 + k0 + kq * 4);
            As[kq * 4 + 0][r] = va.x; As[kq * 4 + 1][r] = va.y; As[kq * 4 + 2][r] = va.z; As[kq * 4 + 3][r] = va.w;
        }
        for (int i = tid; i < 1024; i += 256) {
            int r = i >> 4, nq = i & 15;
            float4 vb = *(const float4*)(Bq + (size_t)(k0 + r) * 192 + col0 + nq * 4);
            Bs[r][nq * 4 + 0] = vb.x; Bs[r][nq * 4 + 1] = vb.y; Bs[r][nq * 4 + 2] = vb.z; Bs[r][nq * 4 + 3] = vb.w;
        }
        __syncthreads();
        for (int k = 0; k < 64; ++k) {
            float a[4], bb[4];
#pragma unroll
            for (int m = 0; m < 4; ++m) a[m] = As[k][ty * 4 + m];
#pragma unroll
            for (int n = 0; n < 4; ++n) bb[n] = Bs[k][tx * 4 + n];
#pragma unroll
            for (int m = 0; m < 4; ++m)
#pragma unroll
                for (int n = 0; n < 4; ++n) acc[m][n] = fmaf(a[m], bb[n], acc[m][n]);
        }
        __syncthreads();
    }
#pragma unroll
    for (int m = 0; m < 4; ++m)
#pragma unroll
        for (int n = 0; n < 4; ++n)
            C[(size_t)(row0 + ty * 4 + m) * 2304 + col0 + tx * 4 + n] = acc[m][n];
}

// fp32 [K][N] -> bf16 [N][K], 32x32 tiles, grid.z = layer
__global__ __launch_bounds__(256) void transpose_bf16_kernel(const float* __restrict__ W,
                                                             unsigned short* __restrict__ Wt,
                                                             int K, int N) {
    __shared__ float t[32][33];
    size_t zoff = (size_t)blockIdx.z * K * N;
    const float* Wz = W + zoff;
    unsigned short* Wtz = Wt + zoff;
    int k0 = blockIdx.y * 32, n0 = blockIdx.x * 32;
    int tid = threadIdx.x;
    int tr = tid >> 3, tc = tid & 7;
    float4 v = *(const float4*)(Wz + (size_t)(k0 + tr) * N + n0 + tc * 4);
    t[tr][tc * 4 + 0] = v.x; t[tr][tc * 4 + 1] = v.y; t[tr][tc * 4 + 2] = v.z; t[tr][tc * 4 + 3] = v.w;
    __syncthreads();
    u16x4 o;
    o[0] = f2bf(t[tc * 4 + 0][tr]); o[1] = f2bf(t[tc * 4 + 1][tr]);
    o[2] = f2bf(t[tc * 4 + 2][tr]); o[3] = f2bf(t[tc * 4 + 3][tr]);
    *(u16x4*)(Wtz + (size_t)(n0 + tr) * K + k0 + tc * 4) = o;
}

__global__ __launch_bounds__(256) void patch_embed_kernel(const float* __restrict__ z_t,
                                                          const float* __restrict__ spins,
                                                          const float* __restrict__ patch_w,
                                                          const float* __restrict__ patch_b,
                                                          float* __restrict__ x) {
    int bs = blockIdx.x;
    int b = bs >> 8, s = bs & 255;
    int gy = s >> 4, gx = s & 15;
    __shared__ float in20[20];
    int t = threadIdx.x;
    if (t < 12) {
        int c = t >> 2, py = (t >> 1) & 1, px = t & 1;
        in20[t] = z_t[(((size_t)b * 3 + c) * 32 + (2 * gy + py)) * 32 + (2 * gx + px)];
    } else if (t < 20) {
        in20[t] = spins[b * 8 + (t - 12)];
    }
    __syncthreads();
    for (int d = t; d < 768; d += 256) {
        float acc = patch_b[d];
#pragma unroll
        for (int i = 0; i < 20; ++i) acc += in20[i] * patch_w[i * 768 + d];
        x[(size_t)bs * 768 + d] = acc;
    }
}

// fp32 x -> bf16 h (rmsnorm)
__global__ __launch_bounds__(256) void rmsnorm_kernel(const float* __restrict__ x,
                                                      unsigned short* __restrict__ h) {
    int row = blockIdx.x, t = threadIdx.x;
    const float* xr = x + (size_t)row * 768;
    float a0 = xr[t], a1 = xr[t + 256], a2 = xr[t + 512];
    __shared__ float red[256];
    red[t] = a0 * a0 + a1 * a1 + a2 * a2;
    __syncthreads();
    for (int s = 128; s > 0; s >>= 1) { if (t < s) red[t] += red[t + s]; __syncthreads(); }
    float sc = 1.0f / sqrtf(red[0] / 768.0f + EPS_RMS);
    unsigned short* hr = h + (size_t)row * 768;
    hr[t] = f2bf(a0 * sc); hr[t + 256] = f2bf(a1 * sc); hr[t + 512] = f2bf(a2 * sc);
}

// ---- bf16 MFMA GEMM: A[M][K] bf16, Bt[N][K] bf16 -> C[M][N] ---------------
// 128x128 tile, BK=32, 4 waves (2x2), 4x4 16x16 fragments per wave.
// EPI: 0=store bf16(+bias)  1=qkv scatter  2=gate  3=val*gelu(g)  4=x+=v
template <int EPI>
__global__ __launch_bounds__(256) void gemm_mfma(const unsigned short* __restrict__ A, int lda,
                                                 const unsigned short* __restrict__ Bt, int ldb,
                                                 unsigned short* __restrict__ Cb, int ldc, int K,
                                                 const float* __restrict__ bias,
                                                 float* __restrict__ Xf,
                                                 const unsigned short* __restrict__ Pb) {
    __shared__ unsigned short As[4096];   // [128 rows][32 k] with chunk swizzle
    __shared__ unsigned short Bs[4096];
    int tid = threadIdx.x;
    int wave = tid >> 6, lane = tid & 63;
    int row0 = blockIdx.y * 128, col0 = blockIdx.x * 128;
    int wm = wave >> 1, wn = wave & 1;
    f32x4 acc[4][4] = {};

    // staging: lane writes LDS linearly at chunk*1024B + lane*16B
    //  -> row = chunk*16 + lane/4, k-chunk slot c = lane&3
    //  physical slot c holds global k-chunk (c ^ (row&3))  [involution]
    int srow = lane >> 2;                              // row within chunk
    int ksw = (((lane & 3) ^ (srow & 3)) * 8);         // pre-swizzled source k-offset
    // fragment read: logical k-chunk (lane>>4) of row (..+lane&15)
    int lrow = lane & 15;
    int csw = (((lane >> 4) ^ (lane & 3)) * 8);        // swizzled LDS k-offset

    for (int k0 = 0; k0 < K; k0 += 32) {
#pragma unroll
        for (int it = 0; it < 2; ++it) {
            int chunk = it * 4 + wave;
            int r = chunk * 16 + srow;
            gload16(A  + (size_t)(row0 + r) * lda + k0 + ksw, &As[chunk * 512]);
            gload16(Bt + (size_t)(col0 + r) * ldb + k0 + ksw, &Bs[chunk * 512]);
        }
        __syncthreads();
        s16x8 af[4], bf[4];
#pragma unroll
        for (int m = 0; m < 4; ++m)
            af[m] = *(const s16x8*)&As[(wm * 64 + m * 16 + lrow) * 32 + csw];
#pragma unroll
        for (int n = 0; n < 4; ++n)
            bf[n] = *(const s16x8*)&Bs[(wn * 64 + n * 16 + lrow) * 32 + csw];
#pragma unroll
        for (int m = 0; m < 4; ++m)
#pragma unroll
            for (int n = 0; n < 4; ++n)
                acc[m][n] = __builtin_amdgcn_mfma_f32_16x16x32_bf16(af[m], bf[n], acc[m][n], 0, 0, 0);
        __syncthreads();
    }

    int lquad = lane >> 4;
#pragma unroll
    for (int m = 0; m < 4; ++m) {
#pragma unroll
        for (int n = 0; n < 4; ++n) {
#pragma unroll
            for (int r = 0; r < 4; ++r) {
                int i = row0 + wm * 64 + m * 16 + lquad * 4 + r;
                int j = col0 + wn * 64 + n * 16 + lrow;
                float v = acc[m][n][r];
                if (bias) v += bias[j];
                if constexpr (EPI == 0) {
                    Cb[(size_t)i * ldc + j] = f2bf(v);
                } else if constexpr (EPI == 1) {
                    int which = j / 768;
                    int rem = j - which * 768;
                    int head = rem / 192;
                    int hd = rem - head * 192;
                    int b = i >> 8, s = i & 255;
                    Cb[(size_t)which * ARENA_K + (((size_t)(b * 4 + head)) * 256 + s) * 192 + hd] = f2bf(v);
                } else if constexpr (EPI == 2) {
                    float p = b2f(Pb[(size_t)i * 768 + j]);
                    Xf[(size_t)i * 768 + j] += p * sigmoidf_(v);
                } else if constexpr (EPI == 3) {
                    float g = b2f(Cb[(size_t)i * ldc + j]);
                    Cb[(size_t)i * ldc + j] = f2bf(v * geluf_(g));
                } else if constexpr (EPI == 4) {
                    Xf[(size_t)i * ldc + j] += v;
                }
            }
        }
    }
}

// in-place RoPE on bf16 [q|k] (131072 rows x 192), pairs (j, j+96), 4 at a time
__global__ __launch_bounds__(256) void rope_kernel(unsigned short* __restrict__ qk,
                                                   const float* __restrict__ cosb,
                                                   const float* __restrict__ sinb) {
    int gid = blockIdx.x * 256 + threadIdx.x;      // 131072*24
    int row = gid / 24, q4 = gid - row * 24;
    int j0 = q4 * 4;
    int s = row & 255;
    unsigned short* p = qk + (size_t)row * 192;
    u16x4 t1 = *(u16x4*)(p + j0);
    u16x4 t2 = *(u16x4*)(p + 96 + j0);
    u16x4 o1, o2;
#pragma unroll
    for (int i = 0; i < 4; ++i) {
        float a = b2f(t1[i]), b = b2f(t2[i]);
        float c1 = cosb[s * 192 + j0 + i],      s1 = sinb[s * 192 + j0 + i];
        float c2 = cosb[s * 192 + 96 + j0 + i], s2 = sinb[s * 192 + 96 + j0 + i];
        o1[i] = f2bf(a * c1 - b * s1);
        o2[i] = f2bf(b * c2 + a * s2);
    }
    *(u16x4*)(p + j0) = o1;
    *(u16x4*)(p + 96 + j0) = o2;
}

// attention: grid (8 qtiles, NH, B), 256 thr, fp32 compute on bf16 q/k/v
__global__ __launch_bounds__(256) void attn_kernel(const unsigned short* __restrict__ qb_,
                                                   const unsigned short* __restrict__ kb_,
                                                   const unsigned short* __restrict__ vb_,
                                                   unsigned short* __restrict__ attn, int glob) {
    int b = blockIdx.z, h = blockIdx.y, q0 = blockIdx.x * 32;
    const unsigned short* qb = qb_ + ((size_t)(b * 4 + h) * 256) * 192;
    const unsigned short* kb = kb_ + ((size_t)(b * 4 + h) * 256) * 192;
    const unsigned short* vb = vb_ + ((size_t)(b * 4 + h) * 256) * 192;
    __shared__ float qs[32][194];
    __shared__ float ks[64][193];
    __shared__ float sc[32][257];
    __shared__ float red8[32][9];
    int t = threadIdx.x;
    for (int i = t; i < 768; i += 256) {           // 32 rows * 24 chunks
        int r = i / 24, f = i - r * 24;
        u16x8 v8 = *(const u16x8*)(qb + (size_t)(q0 + r) * 192 + f * 8);
#pragma unroll
        for (int j = 0; j < 8; ++j) qs[r][f * 8 + j] = b2f(v8[j]);
    }
    int qr = t >> 3, l8 = t & 7;
    int sq = q0 + qr, yq = sq >> 4, xq = sq & 15;
    for (int kt = 0; kt < 4; ++kt) {
        __syncthreads();
        for (int i = t; i < 1536; i += 256) {      // 64 rows * 24 chunks
            int r = i / 24, f = i - r * 24;
            u16x8 v8 = *(const u16x8*)(kb + (size_t)(kt * 64 + r) * 192 + f * 8);
#pragma unroll
            for (int j = 0; j < 8; ++j) ks[r][f * 8 + j] = b2f(v8[j]);
        }
        __syncthreads();
        int kc0 = l8 * 8;
        float a8[8] = {};
        for (int d = 0; d < 192; ++d) {
            float qv = qs[qr][d];
#pragma unroll
            for (int i = 0; i < 8; ++i) a8[i] = fmaf(qv, ks[kc0 + i][d], a8[i]);
        }
#pragma unroll
        for (int i = 0; i < 8; ++i) {
            int sk = kt * 64 + kc0 + i, yk = sk >> 4, xk = sk & 15;
            int dy = yq - yk, dx = xq - xk;
            bool keep = glob || (dy * dy + dx * dx) < 7;
            sc[qr][kt * 64 + kc0 + i] = keep ? a8[i] * ATT_SCALE : -1e30f;
        }
    }
    __syncthreads();
    float m = -3e38f;
    for (int c = l8; c < 256; c += 8) m = fmaxf(m, sc[qr][c]);
    red8[qr][l8] = m;
    __syncthreads();
    if (l8 == 0) { float mm = red8[qr][0]; for (int i = 1; i < 8; ++i) mm = fmaxf(mm, red8[qr][i]); red8[qr][8] = mm; }
    __syncthreads();
    float rm = red8[qr][8];
    float e = 0.f;
    for (int c = l8; c < 256; c += 8) { float p = expf(sc[qr][c] - rm); sc[qr][c] = p; e += p; }
    __syncthreads();
    red8[qr][l8] = e;
    __syncthreads();
    if (l8 == 0) { float ss = 0.f; for (int i = 0; i < 8; ++i) ss += red8[qr][i]; red8[qr][8] = ss; }
    __syncthreads();
    float inv = 1.0f / red8[qr][8];
    for (int c = l8; c < 256; c += 8) sc[qr][c] *= inv;
    float out[24] = {};
    int d0 = l8 * 24;
    for (int vt = 0; vt < 4; ++vt) {
        __syncthreads();
        for (int i = t; i < 1536; i += 256) {
            int r = i / 24, f = i - r * 24;
            u16x8 v8 = *(const u16x8*)(vb + (size_t)(vt * 64 + r) * 192 + f * 8);
#pragma unroll
            for (int j = 0; j < 8; ++j) ks[r][f * 8 + j] = b2f(v8[j]);
        }
        __syncthreads();
        for (int kc = 0; kc < 64; ++kc) {
            float p = sc[qr][vt * 64 + kc];
#pragma unroll
            for (int i = 0; i < 24; ++i) out[i] = fmaf(p, ks[kc][d0 + i], out[i]);
        }
    }
    unsigned short* dst = attn + ((size_t)(b * 256 + (q0 + qr))) * 768 + h * 192 + d0;
#pragma unroll
    for (int i = 0; i < 24; ++i) dst[i] = f2bf(out[i]);
}

__global__ __launch_bounds__(768) void scalef_kernel(const float* __restrict__ spins,
                                                     const float* __restrict__ sd1_w,
                                                     const float* __restrict__ sd1_b,
                                                     const float* __restrict__ sd2_w,
                                                     const float* __restrict__ sd2_b,
                                                     float* __restrict__ scalef) {
    int b = blockIdx.x, t = threadIdx.x;
    __shared__ float hid[768];
    __shared__ float sp[8];
    if (t < 8) sp[t] = spins[b * 8 + t];
    __syncthreads();
    float acc = sd1_b[t];
#pragma unroll
    for (int i = 0; i < 8; ++i) acc += sp[i] * sd1_w[i * 768 + t];
    hid[t] = acc * sigmoidf_(acc);
    __syncthreads();
    if (t < 12) {
        float o = sd2_b[t];
        for (int d = 0; d < 768; ++d) o += hid[d] * sd2_w[d * 12 + t];
        scalef[b * 12 + t] = expf(o);
    }
}

__global__ __launch_bounds__(192) void head_kernel(const unsigned short* __restrict__ xn,
                                                   const float* __restrict__ head_w,
                                                   const float* __restrict__ head_b,
                                                   const float* __restrict__ scalef,
                                                   float* __restrict__ out) {
    int bs = blockIdx.x;
    int b = bs >> 8, s = bs & 255;
    int t = threadIdx.x;
    int o = t >> 4, part = t & 15;
    const unsigned short* xr = xn + (size_t)bs * 768;
    float acc = 0.f;
    for (int d = part * 48; d < part * 48 + 48; ++d) acc += b2f(xr[d]) * head_w[d * 12 + o];
    __shared__ float red[12][17];
    red[o][part] = acc;
    __syncthreads();
    if (t < 12) {
        float v = head_b[t];
        for (int i = 0; i < 16; ++i) v += red[t][i];
        v *= scalef[b * 12 + t];
        int c = t >> 2, py = (t >> 1) & 1, px = t & 1;
        int gy = s >> 4, gx = s & 15;
        out[(((size_t)b * 3 + c) * 32 + 2 * gy + py) * 32 + 2 * gx + px] = v;
    }
}

__global__ __launch_bounds__(256) void lpred_kernel(const unsigned short* __restrict__ xn,
                                                    const float* __restrict__ lam_w,
                                                    const float* __restrict__ lam_b,
                                                    float* __restrict__ out) {
    int b = blockIdx.x, t = threadIdx.x;
    float a0 = 0.f, a1 = 0.f, a2 = 0.f;
    const unsigned short* xb = xn + (size_t)b * 256 * 768;
    for (int s = 0; s < 256; ++s) {
        const unsigned short* xr = xb + (size_t)s * 768;
        a0 += b2f(xr[t]); a1 += b2f(xr[t + 256]); a2 += b2f(xr[t + 512]);
    }
    float p = a0 * lam_w[t] + a1 * lam_w[t + 256] + a2 * lam_w[t + 512];
    __shared__ float red[256];
    red[t] = p;
    __syncthreads();
    for (int s2 = 128; s2 > 0; s2 >>= 1) { if (t < s2) red[t] += red[t + s2]; __syncthreads(); }
    if (t == 0) out[196608 + b] = red[0] / 256.0f + lam_b[0];
}

// ---------------------------------------------------------------------------
extern "C" void kernel_launch(void* const* d_in, const int* in_sizes, int n_in,
                              void* d_out, int out_size, void* d_ws, size_t ws_size,
                              hipStream_t stream) {
    const float* z_t     = (const float*)d_in[0];
    const float* logsnr  = (const float*)d_in[1];
    const float* qkv_w   = (const float*)d_in[2];
    const float* out_w   = (const float*)d_in[3];
    const float* gate_w  = (const float*)d_in[4];
    const float* gate_b  = (const float*)d_in[5];
    const float* mlpg_w  = (const float*)d_in[6];
    const float* mlpg_b  = (const float*)d_in[7];
    const float* mlpo_w  = (const float*)d_in[8];
    const float* mlpo_b  = (const float*)d_in[9];
    const float* hh_vs   = (const float*)d_in[10];
    const float* patch_w = (const float*)d_in[11];
    const float* patch_b = (const float*)d_in[12];
    const float* head_w  = (const float*)d_in[13];
    const float* head_b  = (const float*)d_in[14];
    const float* sd1_w   = (const float*)d_in[15];
    const float* sd1_b   = (const float*)d_in[16];
    const float* sd2_w   = (const float*)d_in[17];
    const float* sd2_b   = (const float*)d_in[18];
    const float* lam_w   = (const float*)d_in[19];
    const float* lam_b   = (const float*)d_in[20];

    char* wsb = (char*)d_ws;
    float* spins  = (float*)(wsb + B_SPINS);
    float* scalef = (float*)(wsb + B_SCALEF);
    float* qt     = (float*)(wsb + B_QT);
    float* cosb   = (float*)(wsb + B_COS);
    float* sinb   = (float*)(wsb + B_SIN);
    float* x      = (float*)(wsb + B_X);
    unsigned short* h      = (unsigned short*)(wsb + B_H);
    unsigned short* proj   = (unsigned short*)(wsb + B_PROJ);
    unsigned short* weff_t = (unsigned short*)(wsb + B_WEFFT);
    unsigned short* outw_t = (unsigned short*)(wsb + B_OUTWT);
    unsigned short* gatew_t= (unsigned short*)(wsb + B_GATEWT);
    unsigned short* mlpg_t = (unsigned short*)(wsb + B_MLPGT);
    unsigned short* mlpo_t = (unsigned short*)(wsb + B_MLPOT);
    unsigned short* arena  = (unsigned short*)(wsb + B_ARENA);
    unsigned short* qbuf = arena;
    unsigned short* kbuf = arena + ARENA_K;
    unsigned short* vbuf = arena + 2 * ARENA_K;
    unsigned short* attnb = arena + 3 * ARENA_K;
    unsigned short* hidden = arena;                  // aliases q/k/v/attn
    float* weff_f = (float*)(wsb + B_ARENA);         // fp32 tmp during setup
    float* out = (float*)d_out;

    // ---- setup ----
    spins_kernel<<<1, 64, 0, stream>>>(logsnr, spins);
    rope_table_kernel<<<256, 192, 0, stream>>>(cosb, sinb);
    householder_kernel<<<8, 256, 0, stream>>>(hh_vs, qt);
    hipMemcpyAsync(weff_f, qkv_w, (size_t)Ll * Dd * 3 * Dd * sizeof(float),
                   hipMemcpyDeviceToDevice, stream);
    fold_kernel<<<dim3(3, 12, 64), 256, 0, stream>>>(qkv_w, qt, weff_f);
    transpose_bf16_kernel<<<dim3(72, 24, 8), 256, 0, stream>>>(weff_f, weff_t, 768, 2304);
    transpose_bf16_kernel<<<dim3(24, 24, 8), 256, 0, stream>>>(out_w, outw_t, 768, 768);
    transpose_bf16_kernel<<<dim3(24, 24, 8), 256, 0, stream>>>(gate_w, gatew_t, 768, 768);
    transpose_bf16_kernel<<<dim3(192, 24, 8), 256, 0, stream>>>(mlpg_w, mlpg_t, 768, 6144);
    transpose_bf16_kernel<<<dim3(24, 96, 8), 256, 0, stream>>>(mlpo_w, mlpo_t, 3072, 768);
    patch_embed_kernel<<<M_TOK, 256, 0, stream>>>(z_t, spins, patch_w, patch_b, x);

    for (int l = 0; l < Ll; ++l) {
        int glob = ((l + 1) % 4 == 0) ? 1 : 0;
        rmsnorm_kernel<<<M_TOK, 256, 0, stream>>>(x, h);
        gemm_mfma<1><<<dim3(18, 128), 256, 0, stream>>>(h, 768,
            weff_t + (size_t)l * 2304 * 768, 768, arena, 0, 768, nullptr, nullptr, nullptr);
        rope_kernel<<<12288, 256, 0, stream>>>(arena, cosb, sinb);
        attn_kernel<<<dim3(8, 4, 64), 256, 0, stream>>>(qbuf, kbuf, vbuf, attnb, glob);
        gemm_mfma<0><<<dim3(6, 128), 256, 0, stream>>>(attnb, 768,
            outw_t + (size_t)l * 768 * 768, 768, proj, 768, 768, nullptr, nullptr, nullptr);
        gemm_mfma<2><<<dim3(6, 128), 256, 0, stream>>>(proj, 768,
            gatew_t + (size_t)l * 768 * 768, 768, nullptr, 768, 768,
            gate_b + (size_t)l * 768, x, proj);
        rmsnorm_kernel<<<M_TOK, 256, 0, stream>>>(x, h);
        gemm_mfma<0><<<dim3(24, 128), 256, 0, stream>>>(h, 768,
            mlpg_t + (size_t)l * 6144 * 768, 768, hidden, 3072, 768,
            mlpg_b + (size_t)l * 6144, nullptr, nullptr);
        gemm_mfma<3><<<dim3(24, 128), 256, 0, stream>>>(h, 768,
            mlpg_t + (size_t)l * 6144 * 768 + (size_t)3072 * 768, 768, hidden, 3072, 768,
            mlpg_b + (size_t)l * 6144 + 3072, nullptr, nullptr);
        gemm_mfma<4><<<dim3(6, 128), 256, 0, stream>>>(hidden, 3072,
            mlpo_t + (size_t)l * 768 * 3072, 3072, nullptr, 768, 3072,
            mlpo_b + (size_t)l * 768, x, nullptr);
    }

    rmsnorm_kernel<<<M_TOK, 256, 0, stream>>>(x, h);
    scalef_kernel<<<64, 768, 0, stream>>>(spins, sd1_w, sd1_b, sd2_w, sd2_b, scalef);
    head_kernel<<<M_TOK, 192, 0, stream>>>(h, head_w, head_b, scalef, out);
    lpred_kernel<<<64, 256, 0, stream>>>(h, lam_w, lam_b, out);
}

// Round 3
// 8029.736 us; speedup vs baseline: 5.3745x; 1.7560x over previous
//
#include <hip/hip_runtime.h>
#include <hip/hip_bf16.h>
#include <math.h>

// ---------------------------------------------------------------------------
// HybridGemmaDiT forward.  B=64, S=256 (16x16), D=768, L=8, NH=4, HD=192.
// R3: WY-form householder (4 small kernels) + bf16 MFMA attention
//     (V stored transposed at qkv scatter; full-row softmax in registers).
// ---------------------------------------------------------------------------

#define DEV static __device__ __forceinline__

typedef float    f32x4 __attribute__((ext_vector_type(4)));
typedef short    s16x8 __attribute__((ext_vector_type(8)));
typedef unsigned short u16x8 __attribute__((ext_vector_type(8)));
typedef unsigned short u16x4 __attribute__((ext_vector_type(4)));

constexpr int Bb = 64, Ss = 256, Dd = 768, Ll = 8, NHh = 4, HDd = 192;
constexpr int M_TOK = Bb * Ss;                 // 16384
constexpr float EPS_RMS = 1.1920929e-07f;
constexpr float ATT_SCALE = 0.07216878364870322f;  // 1/sqrt(192)
constexpr size_t ARENA_K = (size_t)Bb * NHh * Ss * HDd;   // 12,582,912 elems

// ---- workspace layout (BYTES) ---------------------------------------------
constexpr size_t B_SPINS  = 0;
constexpr size_t B_SCALEF = 2048;
constexpr size_t B_QT     = 5120;                        // 8*192*192 f32
constexpr size_t B_COS    = B_QT + 1179648;
constexpr size_t B_SIN    = B_COS + 196608;
constexpr size_t B_G      = B_SIN + 196608;              // 8*96*96 f32
constexpr size_t B_T      = B_G + 294912;                // 8*96*96 f32
constexpr size_t B_AWY    = B_T + 294912;                // 8*96*192 f32
constexpr size_t B_X      = B_AWY + 589824;              // 16384*768 f32
constexpr size_t B_H      = B_X + 50331648;              // bf16
constexpr size_t B_PROJ   = B_H + 25165824;              // bf16
constexpr size_t B_WEFFT  = B_PROJ + 25165824;           // 8*2304*768 bf16
constexpr size_t B_OUTWT  = B_WEFFT + 28311552;
constexpr size_t B_GATEWT = B_OUTWT + 9437184;
constexpr size_t B_MLPGT  = B_GATEWT + 9437184;          // 8*6144*768 bf16
constexpr size_t B_MLPOT  = B_MLPGT + 75497472;          // 8*768*3072 bf16
constexpr size_t B_ARENA  = B_MLPOT + 37748736;          // q,k,v^T,attn bf16 | hidden | weff_f32

DEV float sigmoidf_(float x) { return 1.0f / (1.0f + expf(-x)); }
DEV float geluf_(float g)    { return 0.5f * g * (1.0f + erff(g * 0.7071067811865476f)); }
DEV unsigned short f2bf(float f) {
    union { float f; unsigned u; } a; a.f = f;
    unsigned u = a.u + 0x7fffu + ((a.u >> 16) & 1u);
    return (unsigned short)(u >> 16);
}
DEV float b2f(unsigned short u) {
    union { unsigned u; float f; } a; a.u = ((unsigned)u) << 16; return a.f;
}
DEV void gload16(const void* g, void* l) {
    __builtin_amdgcn_global_load_lds((const __attribute__((address_space(1))) void*)g,
                                     (__attribute__((address_space(3))) void*)l, 16, 0, 0);
}

// ---------------------------------------------------------------------------
__global__ void spins_kernel(const float* __restrict__ logsnr, float* __restrict__ spins) {
    int b = threadIdx.x;
    if (b < 64) {
        float v = logsnr[b];
#pragma unroll
        for (int j = 0; j < 4; ++j) {
            float ang = v * (float)(1 << j);
            spins[b * 8 + j]     = sinf(ang);
            spins[b * 8 + 4 + j] = cosf(ang);
        }
    }
}

__global__ void rope_table_kernel(float* __restrict__ cosb, float* __restrict__ sinb) {
    int s = blockIdx.x, j = threadIdx.x;
    int y = s >> 4, x = s & 15;
    int base = j % 96;
    float coord, invf;
    if (base < 48) { invf = expf(-(float)base * (2.0f / 96.0f) * 9.210340371976184f); coord = (float)y; }
    else { int i = base - 48; invf = expf(-(float)i * (2.0f / 96.0f) * 9.210340371976184f); coord = (float)x; }
    float f = coord * invf, sv, cv;
    sincosf(f, &sv, &cv);
    cosb[s * 192 + j] = cv;
    sinb[s * 192 + j] = sv;
}

// ---- WY householder: Q = (I - Y T Y^T)^T ; qt = P = I - Y T Y^T ----------
// G[i][j] = y_i . y_j
__global__ __launch_bounds__(256) void hh_gram_kernel(const float* __restrict__ hh_vs,
                                                      float* __restrict__ Gm) {
    __shared__ float Y[96][192];
    int l = blockIdx.x, t = threadIdx.x;
    const float4* src = (const float4*)(hh_vs + (size_t)l * 96 * 192);
    for (int i = t; i < 4608; i += 256) ((float4*)&Y[0][0])[i] = src[i];
    __syncthreads();
    for (int e = t; e < 9216; e += 256) {
        int i = e / 96, j = e - (e / 96) * 96;
        float acc = 0.f;
        for (int d = 0; d < 48; ++d) {
            float4 a = *(const float4*)&Y[i][d * 4];
            float4 b = *(const float4*)&Y[j][d * 4];
            acc += a.x * b.x + a.y * b.y + a.z * b.z + a.w * b.w;
        }
        Gm[(size_t)l * 9216 + e] = acc;
    }
}

// T recurrence: T[j][j]=c_j; T[i][j] = -c_j * sum_{p=i..j-1} T[i][p] G[p][j]
__global__ __launch_bounds__(128) void hh_t_kernel(const float* __restrict__ Gm,
                                                   float* __restrict__ Tm) {
    __shared__ float G[96][96];
    __shared__ float T[96][100];
    int l = blockIdx.x, t = threadIdx.x;
    const float* Gl = Gm + (size_t)l * 9216;
    for (int i = t; i < 9216; i += 128) { G[i / 96][i % 96] = Gl[i]; }
    for (int i = t; i < 9600; i += 128) { T[i / 100][i % 100] = 0.f; }
    __syncthreads();
    if (t < 96) T[t][t] = 2.0f / (G[t][t] + 1e-8f);
    __syncthreads();
    for (int j = 1; j < 96; ++j) {
        if (t < j) {
            float cj = 2.0f / (G[j][j] + 1e-8f);
            float dot = 0.f;
            for (int p = t; p < j; ++p) dot += T[t][p] * G[p][j];
            T[t][j] = -cj * dot;
        }
        __syncthreads();
    }
    for (int i = t; i < 9216; i += 128) Tm[(size_t)l * 9216 + i] = T[i / 96][i % 96];
}

// A[i][e] = sum_{j=i..95} T[i][j] * Y[j][e]
__global__ __launch_bounds__(256) void hh_a_kernel(const float* __restrict__ Tm,
                                                   const float* __restrict__ hh_vs,
                                                   float* __restrict__ Am) {
    __shared__ float T[96][100];
    __shared__ float Y[96][192];
    int l = blockIdx.x, t = threadIdx.x;
    const float* Tl = Tm + (size_t)l * 9216;
    const float4* src = (const float4*)(hh_vs + (size_t)l * 96 * 192);
    for (int i = t; i < 9216; i += 256) T[i / 96][i % 96] = Tl[i];
    for (int i = t; i < 4608; i += 256) ((float4*)&Y[0][0])[i] = src[i];
    __syncthreads();
    for (int idx = t; idx < 4608; idx += 256) {       // 96 x 48 (4-wide e)
        int i = idx / 48, e0 = (idx % 48) * 4;
        float4 acc = {0.f, 0.f, 0.f, 0.f};
        for (int j = i; j < 96; ++j) {
            float tv = T[i][j];
            float4 y = *(const float4*)&Y[j][e0];
            acc.x += tv * y.x; acc.y += tv * y.y; acc.z += tv * y.z; acc.w += tv * y.w;
        }
        *(float4*)(Am + (size_t)l * 96 * 192 + (size_t)i * 192 + e0) = acc;
    }
}

// qt[d][e] = (d==e) - sum_i Y[i][d] * A[i][e]
__global__ __launch_bounds__(256) void hh_p_kernel(const float* __restrict__ hh_vs,
                                                   const float* __restrict__ Am,
                                                   float* __restrict__ qt) {
    __shared__ float Y[96][192];
    __shared__ float A[96][192];
    int l = blockIdx.x, t = threadIdx.x;
    const float4* ys = (const float4*)(hh_vs + (size_t)l * 96 * 192);
    const float4* as = (const float4*)(Am + (size_t)l * 96 * 192);
    for (int i = t; i < 4608; i += 256) { ((float4*)&Y[0][0])[i] = ys[i]; ((float4*)&A[0][0])[i] = as[i]; }
    __syncthreads();
    for (int idx = t; idx < 9216; idx += 256) {       // 192 x 48 (4-wide d? no: 4-wide e)
        int d = idx / 48, e0 = (idx % 48) * 4;
        float4 acc = {0.f, 0.f, 0.f, 0.f};
        for (int i = 0; i < 96; ++i) {
            float yv = Y[i][d];
            float4 a = *(const float4*)&A[i][e0];
            acc.x += yv * a.x; acc.y += yv * a.y; acc.z += yv * a.z; acc.w += yv * a.w;
        }
        acc.x = (d == e0 + 0 ? 1.f : 0.f) - acc.x;
        acc.y = (d == e0 + 1 ? 1.f : 0.f) - acc.y;
        acc.z = (d == e0 + 2 ? 1.f : 0.f) - acc.z;
        acc.w = (d == e0 + 3 ? 1.f : 0.f) - acc.w;
        *(float4*)(qt + (size_t)l * 192 * 192 + (size_t)d * 192 + e0) = acc;
    }
}

// W_eff q/k head-blocks <- qkv_w block @ Q^T (fp32).  grid (3, 12, 64).
__global__ __launch_bounds__(256) void fold_kernel(const float* __restrict__ qkv_w,
                                                   const float* __restrict__ qt,
                                                   float* __restrict__ weff) {
    int z = blockIdx.z;
    int l = z >> 3, which = (z >> 2) & 1, head = z & 3;
    const float* A  = qkv_w + (size_t)l * 768 * 2304 + (size_t)which * 768 + head * 192;
    const float* Bq = qt + (size_t)l * 192 * 192;
    float* C        = weff + (size_t)l * 768 * 2304 + (size_t)which * 768 + head * 192;
    int row0 = blockIdx.y * 64, col0 = blockIdx.x * 64;
    __shared__ float As[64][65];
    __shared__ float Bs[64][65];
    int tid = threadIdx.x, tx = tid & 15, ty = tid >> 4;
    float acc[4][4] = {};
    for (int k0 = 0; k0 < 192; k0 += 64) {
        for (int i = tid; i < 1024; i += 256) {
            int r = i >> 4, kq = i & 15;
            float4 va = *(const float4*)(A + (size_t)(row0 + r) * 2304 + k0 + kq * 4);
            As[kq * 4 + 0][r] = va.x; As[kq * 4 + 1][r] = va.y; As[kq * 4 + 2][r] = va.z; As[kq * 4 + 3][r] = va.w;
        }
        for (int i = tid; i < 1024; i += 256) {
            int r = i >> 4, nq = i & 15;
            float4 vb = *(const float4*)(Bq + (size_t)(k0 + r) * 192 + col0 + nq * 4);
            Bs[r][nq * 4 + 0] = vb.x; Bs[r][nq * 4 + 1] = vb.y; Bs[r][nq * 4 + 2] = vb.z; Bs[r][nq * 4 + 3] = vb.w;
        }
        __syncthreads();
        for (int k = 0; k < 64; ++k) {
            float a[4], bb[4];
#pragma unroll
            for (int m = 0; m < 4; ++m) a[m] = As[k][ty * 4 + m];
#pragma unroll
            for (int n = 0; n < 4; ++n) bb[n] = Bs[k][tx * 4 + n];
#pragma unroll
            for (int m = 0; m < 4; ++m)
#pragma unroll
                for (int n = 0; n < 4; ++n) acc[m][n] = fmaf(a[m], bb[n], acc[m][n]);
        }
        __syncthreads();
    }
#pragma unroll
    for (int m = 0; m < 4; ++m)
#pragma unroll
        for (int n = 0; n < 4; ++n)
            C[(size_t)(row0 + ty * 4 + m) * 2304 + col0 + tx * 4 + n] = acc[m][n];
}

// fp32 [K][N] -> bf16 [N][K]
__global__ __launch_bounds__(256) void transpose_bf16_kernel(const float* __restrict__ W,
                                                             unsigned short* __restrict__ Wt,
                                                             int K, int N) {
    __shared__ float t[32][33];
    size_t zoff = (size_t)blockIdx.z * K * N;
    const float* Wz = W + zoff;
    unsigned short* Wtz = Wt + zoff;
    int k0 = blockIdx.y * 32, n0 = blockIdx.x * 32;
    int tid = threadIdx.x;
    int tr = tid >> 3, tc = tid & 7;
    float4 v = *(const float4*)(Wz + (size_t)(k0 + tr) * N + n0 + tc * 4);
    t[tr][tc * 4 + 0] = v.x; t[tr][tc * 4 + 1] = v.y; t[tr][tc * 4 + 2] = v.z; t[tr][tc * 4 + 3] = v.w;
    __syncthreads();
    u16x4 o;
    o[0] = f2bf(t[tc * 4 + 0][tr]); o[1] = f2bf(t[tc * 4 + 1][tr]);
    o[2] = f2bf(t[tc * 4 + 2][tr]); o[3] = f2bf(t[tc * 4 + 3][tr]);
    *(u16x4*)(Wtz + (size_t)(n0 + tr) * K + k0 + tc * 4) = o;
}

__global__ __launch_bounds__(256) void patch_embed_kernel(const float* __restrict__ z_t,
                                                          const float* __restrict__ spins,
                                                          const float* __restrict__ patch_w,
                                                          const float* __restrict__ patch_b,
                                                          float* __restrict__ x) {
    int bs = blockIdx.x;
    int b = bs >> 8, s = bs & 255;
    int gy = s >> 4, gx = s & 15;
    __shared__ float in20[20];
    int t = threadIdx.x;
    if (t < 12) {
        int c = t >> 2, py = (t >> 1) & 1, px = t & 1;
        in20[t] = z_t[(((size_t)b * 3 + c) * 32 + (2 * gy + py)) * 32 + (2 * gx + px)];
    } else if (t < 20) {
        in20[t] = spins[b * 8 + (t - 12)];
    }
    __syncthreads();
    for (int d = t; d < 768; d += 256) {
        float acc = patch_b[d];
#pragma unroll
        for (int i = 0; i < 20; ++i) acc += in20[i] * patch_w[i * 768 + d];
        x[(size_t)bs * 768 + d] = acc;
    }
}

__global__ __launch_bounds__(256) void rmsnorm_kernel(const float* __restrict__ x,
                                                      unsigned short* __restrict__ h) {
    int row = blockIdx.x, t = threadIdx.x;
    const float* xr = x + (size_t)row * 768;
    float a0 = xr[t], a1 = xr[t + 256], a2 = xr[t + 512];
    __shared__ float red[256];
    red[t] = a0 * a0 + a1 * a1 + a2 * a2;
    __syncthreads();
    for (int s = 128; s > 0; s >>= 1) { if (t < s) red[t] += red[t + s]; __syncthreads(); }
    float sc = 1.0f / sqrtf(red[0] / 768.0f + EPS_RMS);
    unsigned short* hr = h + (size_t)row * 768;
    hr[t] = f2bf(a0 * sc); hr[t + 256] = f2bf(a1 * sc); hr[t + 512] = f2bf(a2 * sc);
}

// ---- bf16 MFMA GEMM: A[M][K] bf16, Bt[N][K] bf16 -> C[M][N] ---------------
// EPI: 0=store bf16(+bias)  1=qkv scatter (V transposed)  2=gate  3=val*gelu  4=x+=v
template <int EPI>
__global__ __launch_bounds__(256) void gemm_mfma(const unsigned short* __restrict__ A, int lda,
                                                 const unsigned short* __restrict__ Bt, int ldb,
                                                 unsigned short* __restrict__ Cb, int ldc, int K,
                                                 const float* __restrict__ bias,
                                                 float* __restrict__ Xf,
                                                 const unsigned short* __restrict__ Pb) {
    __shared__ unsigned short As[4096];
    __shared__ unsigned short Bs[4096];
    int tid = threadIdx.x;
    int wave = tid >> 6, lane = tid & 63;
    int row0 = blockIdx.y * 128, col0 = blockIdx.x * 128;
    int wm = wave >> 1, wn = wave & 1;
    f32x4 acc[4][4] = {};

    int srow = lane >> 2;
    int ksw = (((lane & 3) ^ (srow & 3)) * 8);
    int lrow = lane & 15;
    int csw = (((lane >> 4) ^ (lane & 3)) * 8);

    for (int k0 = 0; k0 < K; k0 += 32) {
#pragma unroll
        for (int it = 0; it < 2; ++it) {
            int chunk = it * 4 + wave;
            int r = chunk * 16 + srow;
            gload16(A  + (size_t)(row0 + r) * lda + k0 + ksw, &As[chunk * 512]);
            gload16(Bt + (size_t)(col0 + r) * ldb + k0 + ksw, &Bs[chunk * 512]);
        }
        __syncthreads();
        s16x8 af[4], bf[4];
#pragma unroll
        for (int m = 0; m < 4; ++m)
            af[m] = *(const s16x8*)&As[(wm * 64 + m * 16 + lrow) * 32 + csw];
#pragma unroll
        for (int n = 0; n < 4; ++n)
            bf[n] = *(const s16x8*)&Bs[(wn * 64 + n * 16 + lrow) * 32 + csw];
#pragma unroll
        for (int m = 0; m < 4; ++m)
#pragma unroll
            for (int n = 0; n < 4; ++n)
                acc[m][n] = __builtin_amdgcn_mfma_f32_16x16x32_bf16(af[m], bf[n], acc[m][n], 0, 0, 0);
        __syncthreads();
    }

    int lquad = lane >> 4;
#pragma unroll
    for (int m = 0; m < 4; ++m) {
#pragma unroll
        for (int n = 0; n < 4; ++n) {
#pragma unroll
            for (int r = 0; r < 4; ++r) {
                int i = row0 + wm * 64 + m * 16 + lquad * 4 + r;
                int j = col0 + wn * 64 + n * 16 + lrow;
                float v = acc[m][n][r];
                if (bias) v += bias[j];
                if constexpr (EPI == 0) {
                    Cb[(size_t)i * ldc + j] = f2bf(v);
                } else if constexpr (EPI == 1) {
                    int which = j / 768;
                    int rem = j - which * 768;
                    int head = rem / 192;
                    int hd = rem - head * 192;
                    int b = i >> 8, s = i & 255;
                    if (which == 2) {   // V transposed: [bh][d][s]
                        Cb[2 * ARENA_K + (((size_t)(b * 4 + head)) * 192 + hd) * 256 + s] = f2bf(v);
                    } else {
                        Cb[(size_t)which * ARENA_K + (((size_t)(b * 4 + head)) * 256 + s) * 192 + hd] = f2bf(v);
                    }
                } else if constexpr (EPI == 2) {
                    float p = b2f(Pb[(size_t)i * 768 + j]);
                    Xf[(size_t)i * 768 + j] += p * sigmoidf_(v);
                } else if constexpr (EPI == 3) {
                    float g = b2f(Cb[(size_t)i * ldc + j]);
                    Cb[(size_t)i * ldc + j] = f2bf(v * geluf_(g));
                } else if constexpr (EPI == 4) {
                    Xf[(size_t)i * ldc + j] += v;
                }
            }
        }
    }
}

// in-place RoPE on bf16 [q|k] (131072 rows x 192)
__global__ __launch_bounds__(256) void rope_kernel(unsigned short* __restrict__ qk,
                                                   const float* __restrict__ cosb,
                                                   const float* __restrict__ sinb) {
    int gid = blockIdx.x * 256 + threadIdx.x;
    int row = gid / 24, q4 = gid - row * 24;
    int j0 = q4 * 4;
    int s = row & 255;
    unsigned short* p = qk + (size_t)row * 192;
    u16x4 t1 = *(u16x4*)(p + j0);
    u16x4 t2 = *(u16x4*)(p + 96 + j0);
    u16x4 o1, o2;
#pragma unroll
    for (int i = 0; i < 4; ++i) {
        float a = b2f(t1[i]), b = b2f(t2[i]);
        float c1 = cosb[s * 192 + j0 + i],      s1 = sinb[s * 192 + j0 + i];
        float c2 = cosb[s * 192 + 96 + j0 + i], s2 = sinb[s * 192 + 96 + j0 + i];
        o1[i] = f2bf(a * c1 - b * s1);
        o2[i] = f2bf(b * c2 + a * s2);
    }
    *(u16x4*)(p + j0) = o1;
    *(u16x4*)(p + 96 + j0) = o2;
}

// ---- MFMA attention: grid (2 halves, NH, B), 512 thr (8 waves x 16 qrows) -
// K in LDS [256][200]; Vt (global [d][s]) staged per 64-col tile; P per-wave.
__global__ __launch_bounds__(512) void attn_mfma_kernel(const unsigned short* __restrict__ qb_,
                                                        const unsigned short* __restrict__ kb_,
                                                        const unsigned short* __restrict__ vtb_,
                                                        unsigned short* __restrict__ attnb,
                                                        int glob) {
    __shared__ unsigned short Klds[256 * 200];   // 102400 B
    __shared__ unsigned short Vlds[192 * 72];    //  27648 B
    __shared__ unsigned short Plds[8 * 16 * 72]; //  18432 B
    int b = blockIdx.z, hh = blockIdx.y;
    int tid = threadIdx.x;
    int wave = tid >> 6, lane = tid & 63;
    int q0 = blockIdx.x * 128 + wave * 16;
    size_t bh = (size_t)(b * 4 + hh);
    const unsigned short* qb  = qb_  + bh * 49152;   // [s][192]
    const unsigned short* kb  = kb_  + bh * 49152;   // [s][192]
    const unsigned short* vtb = vtb_ + bh * 49152;   // [d][256]

    // stage K
    for (int c = tid; c < 6144; c += 512) {
        int r = c / 24, col = c - (c / 24) * 24;
        *(u16x8*)&Klds[r * 200 + col * 8] = *(const u16x8*)(kb + (size_t)r * 192 + col * 8);
    }
    __syncthreads();

    // Q fragments (global, 16B/lane)
    s16x8 qf[6];
#pragma unroll
    for (int kk = 0; kk < 6; ++kk)
        qf[kk] = *(const s16x8*)(qb + (size_t)(q0 + (lane & 15)) * 192 + kk * 32 + (lane >> 4) * 8);

    // scores: 16 col-frags
    f32x4 sc[16];
#pragma unroll
    for (int n = 0; n < 16; ++n) sc[n] = (f32x4){0.f, 0.f, 0.f, 0.f};
#pragma unroll
    for (int kk = 0; kk < 6; ++kk) {
#pragma unroll
        for (int n = 0; n < 16; ++n) {
            s16x8 bf = *(const s16x8*)&Klds[(n * 16 + (lane & 15)) * 200 + kk * 32 + (lane >> 4) * 8];
            sc[n] = __builtin_amdgcn_mfma_f32_16x16x32_bf16(qf[kk], bf, sc[n], 0, 0, 0);
        }
    }

    // mask + scale
    int lq = (lane >> 4) * 4;        // base local row
#pragma unroll
    for (int n = 0; n < 16; ++n) {
        int sk = n * 16 + (lane & 15);
        int yk = sk >> 4, xk = sk & 15;
#pragma unroll
        for (int r = 0; r < 4; ++r) {
            int sq = q0 + lq + r;
            int dy = (sq >> 4) - yk, dx = (sq & 15) - xk;
            bool keep = glob || (dy * dy + dx * dx) < 7;
            sc[n][r] = keep ? sc[n][r] * ATT_SCALE : -1e30f;
        }
    }
    // row softmax: in-lane over n, cross-lane over (lane&15)
    float rmax[4], rsum[4];
#pragma unroll
    for (int r = 0; r < 4; ++r) {
        float m = sc[0][r];
#pragma unroll
        for (int n = 1; n < 16; ++n) m = fmaxf(m, sc[n][r]);
#pragma unroll
        for (int msk = 1; msk < 16; msk <<= 1) m = fmaxf(m, __shfl_xor(m, msk));
        rmax[r] = m;
    }
#pragma unroll
    for (int r = 0; r < 4; ++r) {
        float e = 0.f;
#pragma unroll
        for (int n = 0; n < 16; ++n) { float p = expf(sc[n][r] - rmax[r]); sc[n][r] = p; e += p; }
#pragma unroll
        for (int msk = 1; msk < 16; msk <<= 1) e += __shfl_xor(e, msk);
        rsum[r] = 1.0f / e;
    }

    // PV over 4 k-tiles of 64
    f32x4 o[12];
#pragma unroll
    for (int n = 0; n < 12; ++n) o[n] = (f32x4){0.f, 0.f, 0.f, 0.f};
    unsigned short* Pw = &Plds[wave * 1152];
    for (int kt = 0; kt < 4; ++kt) {
        // write own P slice (bf16, prob-normalized)
#pragma unroll
        for (int nn = 0; nn < 4; ++nn) {
#pragma unroll
            for (int r = 0; r < 4; ++r)
                Pw[(lq + r) * 72 + nn * 16 + (lane & 15)] = f2bf(sc[kt * 4 + nn][r] * rsum[r]);
        }
        __syncthreads();
        // stage Vt tile [192][64]
        for (int c = tid; c < 1536; c += 512) {
            int r = c >> 3, col = c & 7;
            *(u16x8*)&Vlds[r * 72 + col * 8] = *(const u16x8*)(vtb + (size_t)r * 256 + kt * 64 + col * 8);
        }
        __syncthreads();
        s16x8 af[2];
#pragma unroll
        for (int kk2 = 0; kk2 < 2; ++kk2)
            af[kk2] = *(const s16x8*)&Pw[(lane & 15) * 72 + kk2 * 32 + (lane >> 4) * 8];
#pragma unroll
        for (int n = 0; n < 12; ++n) {
#pragma unroll
            for (int kk2 = 0; kk2 < 2; ++kk2) {
                s16x8 bf = *(const s16x8*)&Vlds[(n * 16 + (lane & 15)) * 72 + kk2 * 32 + (lane >> 4) * 8];
                o[n] = __builtin_amdgcn_mfma_f32_16x16x32_bf16(af[kk2], bf, o[n], 0, 0, 0);
            }
        }
    }
    // write attn output [b*256+s][h*192+d]
#pragma unroll
    for (int n = 0; n < 12; ++n) {
        int d = n * 16 + (lane & 15);
#pragma unroll
        for (int r = 0; r < 4; ++r) {
            int sq = q0 + lq + r;
            attnb[((size_t)(b * 256 + sq)) * 768 + hh * 192 + d] = f2bf(o[n][r]);
        }
    }
}

__global__ __launch_bounds__(768) void scalef_kernel(const float* __restrict__ spins,
                                                     const float* __restrict__ sd1_w,
                                                     const float* __restrict__ sd1_b,
                                                     const float* __restrict__ sd2_w,
                                                     const float* __restrict__ sd2_b,
                                                     float* __restrict__ scalef) {
    int b = blockIdx.x, t = threadIdx.x;
    __shared__ float hid[768];
    __shared__ float sp[8];
    if (t < 8) sp[t] = spins[b * 8 + t];
    __syncthreads();
    float acc = sd1_b[t];
#pragma unroll
    for (int i = 0; i < 8; ++i) acc += sp[i] * sd1_w[i * 768 + t];
    hid[t] = acc * sigmoidf_(acc);
    __syncthreads();
    if (t < 12) {
        float o = sd2_b[t];
        for (int d = 0; d < 768; ++d) o += hid[d] * sd2_w[d * 12 + t];
        scalef[b * 12 + t] = expf(o);
    }
}

__global__ __launch_bounds__(192) void head_kernel(const unsigned short* __restrict__ xn,
                                                   const float* __restrict__ head_w,
                                                   const float* __restrict__ head_b,
                                                   const float* __restrict__ scalef,
                                                   float* __restrict__ out) {
    int bs = blockIdx.x;
    int b = bs >> 8, s = bs & 255;
    int t = threadIdx.x;
    int o = t >> 4, part = t & 15;
    const unsigned short* xr = xn + (size_t)bs * 768;
    float acc = 0.f;
    for (int d = part * 48; d < part * 48 + 48; ++d) acc += b2f(xr[d]) * head_w[d * 12 + o];
    __shared__ float red[12][17];
    red[o][part] = acc;
    __syncthreads();
    if (t < 12) {
        float v = head_b[t];
        for (int i = 0; i < 16; ++i) v += red[t][i];
        v *= scalef[b * 12 + t];
        int c = t >> 2, py = (t >> 1) & 1, px = t & 1;
        int gy = s >> 4, gx = s & 15;
        out[(((size_t)b * 3 + c) * 32 + 2 * gy + py) * 32 + 2 * gx + px] = v;
    }
}

__global__ __launch_bounds__(256) void lpred_kernel(const unsigned short* __restrict__ xn,
                                                    const float* __restrict__ lam_w,
                                                    const float* __restrict__ lam_b,
                                                    float* __restrict__ out) {
    int b = blockIdx.x, t = threadIdx.x;
    float a0 = 0.f, a1 = 0.f, a2 = 0.f;
    const unsigned short* xb = xn + (size_t)b * 256 * 768;
    for (int s = 0; s < 256; ++s) {
        const unsigned short* xr = xb + (size_t)s * 768;
        a0 += b2f(xr[t]); a1 += b2f(xr[t + 256]); a2 += b2f(xr[t + 512]);
    }
    float p = a0 * lam_w[t] + a1 * lam_w[t + 256] + a2 * lam_w[t + 512];
    __shared__ float red[256];
    red[t] = p;
    __syncthreads();
    for (int s2 = 128; s2 > 0; s2 >>= 1) { if (t < s2) red[t] += red[t + s2]; __syncthreads(); }
    if (t == 0) out[196608 + b] = red[0] / 256.0f + lam_b[0];
}

// ---------------------------------------------------------------------------
extern "C" void kernel_launch(void* const* d_in, const int* in_sizes, int n_in,
                              void* d_out, int out_size, void* d_ws, size_t ws_size,
                              hipStream_t stream) {
    const float* z_t     = (const float*)d_in[0];
    const float* logsnr  = (const float*)d_in[1];
    const float* qkv_w   = (const float*)d_in[2];
    const float* out_w   = (const float*)d_in[3];
    const float* gate_w  = (const float*)d_in[4];
    const float* gate_b  = (const float*)d_in[5];
    const float* mlpg_w  = (const float*)d_in[6];
    const float* mlpg_b  = (const float*)d_in[7];
    const float* mlpo_w  = (const float*)d_in[8];
    const float* mlpo_b  = (const float*)d_in[9];
    const float* hh_vs   = (const float*)d_in[10];
    const float* patch_w = (const float*)d_in[11];
    const float* patch_b = (const float*)d_in[12];
    const float* head_w  = (const float*)d_in[13];
    const float* head_b  = (const float*)d_in[14];
    const float* sd1_w   = (const float*)d_in[15];
    const float* sd1_b   = (const float*)d_in[16];
    const float* sd2_w   = (const float*)d_in[17];
    const float* sd2_b   = (const float*)d_in[18];
    const float* lam_w   = (const float*)d_in[19];
    const float* lam_b   = (const float*)d_in[20];

    char* wsb = (char*)d_ws;
    float* spins  = (float*)(wsb + B_SPINS);
    float* scalef = (float*)(wsb + B_SCALEF);
    float* qt     = (float*)(wsb + B_QT);
    float* cosb   = (float*)(wsb + B_COS);
    float* sinb   = (float*)(wsb + B_SIN);
    float* Gm     = (float*)(wsb + B_G);
    float* Tm     = (float*)(wsb + B_T);
    float* Am     = (float*)(wsb + B_AWY);
    float* x      = (float*)(wsb + B_X);
    unsigned short* h      = (unsigned short*)(wsb + B_H);
    unsigned short* proj   = (unsigned short*)(wsb + B_PROJ);
    unsigned short* weff_t = (unsigned short*)(wsb + B_WEFFT);
    unsigned short* outw_t = (unsigned short*)(wsb + B_OUTWT);
    unsigned short* gatew_t= (unsigned short*)(wsb + B_GATEWT);
    unsigned short* mlpg_t = (unsigned short*)(wsb + B_MLPGT);
    unsigned short* mlpo_t = (unsigned short*)(wsb + B_MLPOT);
    unsigned short* arena  = (unsigned short*)(wsb + B_ARENA);
    unsigned short* qbuf = arena;
    unsigned short* kbuf = arena + ARENA_K;
    unsigned short* vtbuf = arena + 2 * ARENA_K;
    unsigned short* attnb = arena + 3 * ARENA_K;
    unsigned short* hidden = arena;
    float* weff_f = (float*)(wsb + B_ARENA);
    float* out = (float*)d_out;

    // ---- setup ----
    spins_kernel<<<1, 64, 0, stream>>>(logsnr, spins);
    rope_table_kernel<<<256, 192, 0, stream>>>(cosb, sinb);
    hh_gram_kernel<<<8, 256, 0, stream>>>(hh_vs, Gm);
    hh_t_kernel<<<8, 128, 0, stream>>>(Gm, Tm);
    hh_a_kernel<<<8, 256, 0, stream>>>(Tm, hh_vs, Am);
    hh_p_kernel<<<8, 256, 0, stream>>>(hh_vs, Am, qt);
    hipMemcpyAsync(weff_f, qkv_w, (size_t)Ll * Dd * 3 * Dd * sizeof(float),
                   hipMemcpyDeviceToDevice, stream);
    fold_kernel<<<dim3(3, 12, 64), 256, 0, stream>>>(qkv_w, qt, weff_f);
    transpose_bf16_kernel<<<dim3(72, 24, 8), 256, 0, stream>>>(weff_f, weff_t, 768, 2304);
    transpose_bf16_kernel<<<dim3(24, 24, 8), 256, 0, stream>>>(out_w, outw_t, 768, 768);
    transpose_bf16_kernel<<<dim3(24, 24, 8), 256, 0, stream>>>(gate_w, gatew_t, 768, 768);
    transpose_bf16_kernel<<<dim3(192, 24, 8), 256, 0, stream>>>(mlpg_w, mlpg_t, 768, 6144);
    transpose_bf16_kernel<<<dim3(24, 96, 8), 256, 0, stream>>>(mlpo_w, mlpo_t, 3072, 768);
    patch_embed_kernel<<<M_TOK, 256, 0, stream>>>(z_t, spins, patch_w, patch_b, x);

    for (int l = 0; l < Ll; ++l) {
        int glob = ((l + 1) % 4 == 0) ? 1 : 0;
        rmsnorm_kernel<<<M_TOK, 256, 0, stream>>>(x, h);
        gemm_mfma<1><<<dim3(18, 128), 256, 0, stream>>>(h, 768,
            weff_t + (size_t)l * 2304 * 768, 768, arena, 0, 768, nullptr, nullptr, nullptr);
        rope_kernel<<<12288, 256, 0, stream>>>(arena, cosb, sinb);
        attn_mfma_kernel<<<dim3(2, 4, 64), 512, 0, stream>>>(qbuf, kbuf, vtbuf, attnb, glob);
        gemm_mfma<0><<<dim3(6, 128), 256, 0, stream>>>(attnb, 768,
            outw_t + (size_t)l * 768 * 768, 768, proj, 768, 768, nullptr, nullptr, nullptr);
        gemm_mfma<2><<<dim3(6, 128), 256, 0, stream>>>(proj, 768,
            gatew_t + (size_t)l * 768 * 768, 768, nullptr, 768, 768,
            gate_b + (size_t)l * 768, x, proj);
        rmsnorm_kernel<<<M_TOK, 256, 0, stream>>>(x, h);
        gemm_mfma<0><<<dim3(24, 128), 256, 0, stream>>>(h, 768,
            mlpg_t + (size_t)l * 6144 * 768, 768, hidden, 3072, 768,
            mlpg_b + (size_t)l * 6144, nullptr, nullptr);
        gemm_mfma<3><<<dim3(24, 128), 256, 0, stream>>>(h, 768,
            mlpg_t + (size_t)l * 6144 * 768 + (size_t)3072 * 768, 768, hidden, 3072, 768,
            mlpg_b + (size_t)l * 6144 + 3072, nullptr, nullptr);
        gemm_mfma<4><<<dim3(6, 128), 256, 0, stream>>>(hidden, 3072,
            mlpo_t + (size_t)l * 768 * 3072, 3072, nullptr, 768, 3072,
            mlpo_b + (size_t)l * 768, x, nullptr);
    }

    rmsnorm_kernel<<<M_TOK, 256, 0, stream>>>(x, h);
    scalef_kernel<<<64, 768, 0, stream>>>(spins, sd1_w, sd1_b, sd2_w, sd2_b, scalef);
    head_kernel<<<M_TOK, 192, 0, stream>>>(h, head_w, head_b, scalef, out);
    lpred_kernel<<<64, 256, 0, stream>>>(h, lam_w, lam_b, out);
}